// Round 5
// baseline (300.815 us; speedup 1.0000x reference)
//
#include <hip/hip_runtime.h>
#include <cstdint>

typedef unsigned short u16;
typedef __bf16 bf16x8 __attribute__((ext_vector_type(8)));
typedef float f32x4 __attribute__((ext_vector_type(4)));

__device__ __forceinline__ u16 f2bf(float f) {
  __bf16 h = (__bf16)f;               // HW v_cvt (RNE) on gfx950
  return __builtin_bit_cast(u16, h);
}
__device__ __forceinline__ float bf2f(u16 u) {
  union { uint32_t u; float f; } v; v.u = ((uint32_t)u) << 16;
  return v.f;
}

// async global->LDS, 16B per lane. LDS dest is wave-uniform base + lane*16.
__device__ __forceinline__ void gload16(const void* g, const void* l) {
  __builtin_amdgcn_global_load_lds(
      (const __attribute__((address_space(1))) uint32_t*)(uintptr_t)g,
      (__attribute__((address_space(3))) uint32_t*)(uintptr_t)l, 16, 0, 0);
}

__device__ __forceinline__ f32x4 mfma16(bf16x8 a, bf16x8 b, f32x4 c) {
  return __builtin_amdgcn_mfma_f32_16x16x32_bf16(a, b, c, 0, 0, 0);
}

// swizzled LDS offset for logical (row, col) in a [*][64] bf16 tile (attn):
__device__ __forceinline__ int swz(int row, int col) {
  return row * 64 + ((((col >> 3) ^ (row & 7)) << 3) | (col & 7));
}

// ---------------- merged prep: cvt + 2 transposes + temb_part ----------------
__device__ __forceinline__ void transpose64(const float* __restrict__ src,
                                            u16* __restrict__ dst, int R, int Cc,
                                            int r0, int c0, u16* t) {
  #pragma unroll
  for (int i = 0; i < 16; i++) {
    int e = i * 256 + threadIdx.x;
    int rl = e >> 6, cl = e & 63;
    t[cl * 66 + rl] = f2bf(src[(size_t)(r0 + rl) * Cc + c0 + cl]);
  }
  __syncthreads();
  #pragma unroll
  for (int i = 0; i < 16; i++) {
    int e = i * 256 + threadIdx.x;
    int ro = e >> 6, co = e & 63;
    dst[(size_t)(c0 + ro) * R + r0 + co] = t[ro * 66 + co];
  }
}

// sections: [0,8192) cvt x->bf16 | [8192,8960) T(Wqkv) | [8960,9216) T(Wp)
//           [9216,9600) temb_part
__global__ __launch_bounds__(256)
void k_prep(const float* __restrict__ x, u16* __restrict__ x_bf,
            const float* __restrict__ Wqkv, u16* __restrict__ WqkvT,
            const float* __restrict__ Wp, u16* __restrict__ WpT,
            const float* __restrict__ temb, const float* __restrict__ Wt,
            float* __restrict__ tpart) {
  __shared__ u16 t[64 * 66];
  int bid = blockIdx.x;
  if (bid < 8192) {                              // ---- cvt (2M float4) ----
    int i = bid * 256 + threadIdx.x;
    float4 v = ((const float4*)x)[i];
    union { u16 s[4]; uint2 u; } o;
    o.s[0] = f2bf(v.x); o.s[1] = f2bf(v.y); o.s[2] = f2bf(v.z); o.s[3] = f2bf(v.w);
    ((uint2*)x_bf)[i] = o.u;
    return;
  }
  bid -= 8192;
  if (bid < 768) {                               // ---- transpose Wqkv [1024][3072] ----
    transpose64(Wqkv, WqkvT, 1024, 3072, (bid / 48) * 64, (bid % 48) * 64, t);
    return;
  }
  bid -= 768;
  if (bid < 256) {                               // ---- transpose Wp [1024][1024] ----
    transpose64(Wp, WpT, 1024, 1024, (bid / 16) * 64, (bid % 16) * 64, t);
    return;
  }
  bid -= 256;                                    // ---- temb_part (384 blocks) ----
  {
    const int j = (bid % 12) * 256 + threadIdx.x;   // 0..3071
    const int k0 = (bid / 12) * 32;
    float acc[8];
    #pragma unroll
    for (int b = 0; b < 8; b++) acc[b] = 0.f;
    #pragma unroll 4
    for (int k = k0; k < k0 + 32; k++) {
      float wv = Wt[(size_t)k * 3072 + j];
      #pragma unroll
      for (int b = 0; b < 8; b++) acc[b] += temb[b * 1024 + k] * wv;
    }
    float* p = tpart + (size_t)(bid / 12) * 24576 + j;
    #pragma unroll
    for (int b = 0; b < 8; b++) p[b * 3072] = acc[b];
  }
}

// ------------- bf16 MFMA GEMM: C[M][Ntot] = A[M][K] @ Bt[N][K]^T -------------
// Block 256M x 128N, 4 waves, wave tile 64M x 128N, BK=32.
// A-DIRECT: each wave owns a distinct 64-row A-slab -> A fragments are loaded
// global->VGPR (4 dwordx4/K32, natural MFMA A-layout, prefetched 1 tile ahead).
// Only B (shared by all 4 waves) goes through LDS (double-buffered, 16 KiB,
// verified conflict-free XOR staging/read swizzle). LDS bytes/K32: 72->40 KB.
// __syncthreads' vmcnt drain doubles as the A-prefetch fence.
// MODE 0: temb_red folded into prologue (tcs[128]); writes qkv bf16.
// MODE 1: plain fp32 out + bias.
template <int MODE>
__global__ __launch_bounds__(256, 2)
void k_gemm(const u16* __restrict__ A, const u16* __restrict__ Bt,
            u16* __restrict__ outb, float* __restrict__ outf,
            const float* __restrict__ bias,
            const float* __restrict__ bt, const float* __restrict__ bqkv,
            const float* __restrict__ tpart, int K, int Ntot) {
  __shared__ u16 Bs[2][4096];                   // 128 rows x 32 (K32) u16, swizzled
  __shared__ float tcs[128];                    // MODE 0 bias slice
  const int m0 = blockIdx.y * 256;
  const int n0 = blockIdx.x * 128;
  const int lane = threadIdx.x & 63;
  const int w = threadIdx.x >> 6;
  const int l15 = lane & 15;
  const int fo = (((lane >> 4) ^ ((lane >> 1) & 3)) << 3);
  const int srow = lane >> 2;
  const int schunk = (((lane & 3) ^ ((lane >> 3) & 3)) << 3);

  // ---- MODE 0: fold temb_red -> tcs (before staging) ----
  if (MODE == 0) {
    if (threadIdx.x < 128) {
      const int bidx = m0 >> 10;
      const int j = n0 + (int)threadIdx.x;
      float a = bt[j] + bqkv[j];
      #pragma unroll
      for (int kt = 0; kt < 32; kt++) a += tpart[(size_t)kt * 24576 + bidx * 3072 + j];
      tcs[threadIdx.x] = a;
    }
    asm volatile("" ::: "memory");
  }

  f32x4 acc[4][8];
  #pragma unroll
  for (int i = 0; i < 4; i++)
    #pragma unroll
    for (int j = 0; j < 8; j++) acc[i][j] = (f32x4){0.f, 0.f, 0.f, 0.f};

  // A-direct: lane reads A[m0 + w*64 + 16i + l15][kt*32 + (lane>>4)*8 + 0..7]
  const u16* Arow = A + (size_t)(m0 + w * 64 + l15) * K + ((lane >> 4) * 8);
  const u16* Bg = Bt + (size_t)(n0 + srow) * K + schunk;

  const int iters = K >> 5;

  // prologue: stage B(0), load A-frags(0)
  #pragma unroll
  for (int tt = 0; tt < 2; tt++) {
    int t = w * 2 + tt;
    gload16(Bg + (size_t)(16 * t) * K, &Bs[0][t * 512]);
  }
  bf16x8 afc[4], afn[4];
  #pragma unroll
  for (int i = 0; i < 4; i++)
    afc[i] = *(const bf16x8*)(Arow + (size_t)(16 * i) * K);

  for (int it = 0; it < iters; it++) {
    __syncthreads();                            // B(cur) staged; A(cur) drained too
    const int cur = it & 1;
    if (it + 1 < iters) {
      const int nxt = cur ^ 1;
      const int k1 = (it + 1) << 5;
      #pragma unroll
      for (int tt = 0; tt < 2; tt++) {
        int t = w * 2 + tt;
        gload16(Bg + (size_t)(16 * t) * K + k1, &Bs[nxt][t * 512]);
      }
      #pragma unroll
      for (int i = 0; i < 4; i++)
        afn[i] = *(const bf16x8*)(Arow + (size_t)(16 * i) * K + k1);
    }
    bf16x8 bfr[8];
    #pragma unroll
    for (int j = 0; j < 8; j++)
      bfr[j] = *(const bf16x8*)&Bs[cur][(16 * j + l15) * 32 + fo];
    #pragma unroll
    for (int i = 0; i < 4; i++)
      #pragma unroll
      for (int j = 0; j < 8; j++)
        acc[i][j] = mfma16(afc[i], bfr[j], acc[i][j]);
    if (it + 1 < iters) {
      #pragma unroll
      for (int i = 0; i < 4; i++) afc[i] = afn[i];
    }
  }

  const int rl = (lane >> 4) * 4;
  #pragma unroll
  for (int i = 0; i < 4; i++) {
    #pragma unroll
    for (int j = 0; j < 8; j++) {
      #pragma unroll
      for (int r = 0; r < 4; r++) {
        int grow = m0 + w * 64 + 16 * i + rl + r;
        int gcol = n0 + 16 * j + l15;
        float v = acc[i][j][r];
        if (MODE == 0) {
          v += tcs[16 * j + l15];
          outb[(size_t)grow * Ntot + gcol] = f2bf(v);
        } else {
          v += bias[gcol];
          outf[(size_t)grow * Ntot + gcol] = v;
        }
      }
    }
  }
}

// ------- fused per-head RMSNorm + axial RoPE (q,k) + V transpose -------
__global__ __launch_bounds__(256)
void k_rrv(const u16* __restrict__ qkv,
           const float* __restrict__ cos_y, const float* __restrict__ sin_y,
           const float* __restrict__ cos_x, const float* __restrict__ sin_x,
           const float* __restrict__ qn_w, const float* __restrict__ kn_w,
           u16* __restrict__ Qo, u16* __restrict__ Ko, u16* __restrict__ VT) {
  __shared__ u16 t[64 * 68];
  const int n0 = blockIdx.x * 64, h = blockIdx.y, b = blockIdx.z;
  const int bh = b * 16 + h;
  const int lane = threadIdx.x & 63, w = threadIdx.x >> 6;
  const int l15 = lane & 15, lg = lane >> 4;
  float4 qw = *(const float4*)(qn_w + l15 * 4);
  float4 kw = *(const float4*)(kn_w + l15 * 4);
  const float sgn = (lane & 4) ? 1.0f : -1.0f;
  const float* ct = (lane & 8) ? cos_x : cos_y;
  const float* st = (lane & 8) ? sin_x : sin_y;
  const float QSCALE = 0.18033688011112042f;     // log2(e)/8

  #pragma unroll
  for (int rr = 0; rr < 4; rr++) {
    int row = n0 + w * 16 + rr * 4 + lg;
    size_t src = (size_t)(b * 1024 + row) * 3072 + h * 64 + l15 * 4;
    uint2 qu = *(const uint2*)(qkv + src);
    uint2 ku = *(const uint2*)(qkv + src + 1024);
    float q[4], k[4];
    q[0] = bf2f((u16)qu.x); q[1] = bf2f((u16)(qu.x >> 16));
    q[2] = bf2f((u16)qu.y); q[3] = bf2f((u16)(qu.y >> 16));
    k[0] = bf2f((u16)ku.x); k[1] = bf2f((u16)(ku.x >> 16));
    k[2] = bf2f((u16)ku.y); k[3] = bf2f((u16)(ku.y >> 16));
    float sq = q[0]*q[0] + q[1]*q[1] + q[2]*q[2] + q[3]*q[3];
    float sk = k[0]*k[0] + k[1]*k[1] + k[2]*k[2] + k[3]*k[3];
    #pragma unroll
    for (int m = 1; m < 16; m <<= 1) {
      sq += __shfl_xor(sq, m);
      sk += __shfl_xor(sk, m);
    }
    float rq = rsqrtf(sq * (1.0f / 64.0f) + 1e-6f);
    float rk = rsqrtf(sk * (1.0f / 64.0f) + 1e-6f);
    float4 cc = *(const float4*)(ct + (size_t)row * 32 + (lane & 7) * 4);
    float4 ss = *(const float4*)(st + (size_t)row * 32 + (lane & 7) * 4);
    float qn[4], kn[4];
    qn[0] = q[0]*rq*qw.x; qn[1] = q[1]*rq*qw.y; qn[2] = q[2]*rq*qw.z; qn[3] = q[3]*rq*qw.w;
    kn[0] = k[0]*rk*kw.x; kn[1] = k[1]*rk*kw.y; kn[2] = k[2]*rk*kw.z; kn[3] = k[3]*rk*kw.w;
    float c[4] = {cc.x, cc.y, cc.z, cc.w};
    float s[4] = {ss.x, ss.y, ss.z, ss.w};
    union { u16 e[4]; uint2 u; } oq, ok;
    #pragma unroll
    for (int j = 0; j < 4; j++) {
      float qp = __shfl_xor(qn[j], 4);
      float kp = __shfl_xor(kn[j], 4);
      oq.e[j] = f2bf((qn[j] * c[j] + sgn * qp * s[j]) * QSCALE);
      ok.e[j] = f2bf(kn[j] * c[j] + sgn * kp * s[j]);
    }
    size_t dst = ((size_t)bh * 1024 + row) * 64 + l15 * 4;
    *(uint2*)(Qo + dst) = oq.u;
    *(uint2*)(Ko + dst) = ok.u;
  }

  // V transpose: qkv v-slice [n][d] -> VT [bh][d][n]
  #pragma unroll
  for (int i = 0; i < 4; i++) {
    int e = i * 256 + threadIdx.x;
    int n = e >> 4, dc = e & 15;
    uint2 v = *(const uint2*)(qkv + (size_t)(b * 1024 + n0 + n) * 3072 + 2048 + h * 64 + dc * 4);
    t[(dc * 4 + 0) * 68 + n] = (u16)v.x;
    t[(dc * 4 + 1) * 68 + n] = (u16)(v.x >> 16);
    t[(dc * 4 + 2) * 68 + n] = (u16)v.y;
    t[(dc * 4 + 3) * 68 + n] = (u16)(v.y >> 16);
  }
  __syncthreads();
  #pragma unroll
  for (int i = 0; i < 4; i++) {
    int e = i * 256 + threadIdx.x;
    int d = e >> 4, nc = e & 15;
    const u16* p = &t[d * 68 + nc * 4];
    uint2 o;
    o.x = (uint32_t)p[0] | ((uint32_t)p[1] << 16);
    o.y = (uint32_t)p[2] | ((uint32_t)p[3] << 16);
    *(uint2*)(VT + ((size_t)bh * 64 + d) * 1024 + n0 + nc * 4) = o;
  }
}

// ---------------- flash attention, 128 q-rows/block, dbuf K/V, 1 barrier/iter ----------------
__global__ __launch_bounds__(256, 2)
void k_attn(const u16* __restrict__ Q, const u16* __restrict__ Kb,
            const u16* __restrict__ VT, u16* __restrict__ Ob) {
  __shared__ u16 Ks[2][4096], VTs[2][4096], Ps[4][2048];
  const int lane = threadIdx.x & 63;
  const int w = threadIdx.x >> 6;
  const int bh = blockIdx.x;
  const int qt = blockIdx.y;
  const int b = bh >> 4, h = bh & 15;
  const size_t base = (size_t)bh * 65536;
  const int q0 = qt * 128;
  const int scol = ((lane & 7) ^ (lane >> 3)) * 8;
  const int lr = lane >> 3;

  bf16x8 aq[2][2];
  #pragma unroll
  for (int i = 0; i < 2; i++)
    #pragma unroll
    for (int s = 0; s < 2; s++)
      aq[i][s] = *(const bf16x8*)(Q + base +
          (size_t)(q0 + w * 32 + i * 16 + (lane & 15)) * 64 + s * 32 + (lane >> 4) * 8);

  f32x4 acc_o[2][4];
  float lpar[2][4];
  #pragma unroll
  for (int i = 0; i < 2; i++)
    #pragma unroll
    for (int r = 0; r < 4; r++) {
      acc_o[i][r] = (f32x4){0.f, 0.f, 0.f, 0.f};
      lpar[i][r] = 0.f;
    }

  #pragma unroll
  for (int tt = 0; tt < 2; tt++) {
    int t = w * 2 + tt;
    gload16(Kb + base + (size_t)(8 * t + lr) * 64 + scol, &Ks[0][t * 512]);
    gload16(VT + base + (size_t)(8 * t + lr) * 1024 + scol, &VTs[0][t * 512]);
  }

  for (int it = 0; it < 16; it++) {
    __syncthreads();
    const int cur = it & 1;
    if (it < 15) {
      const int nxt = cur ^ 1;
      const int j1 = (it + 1) * 64;
      #pragma unroll
      for (int tt = 0; tt < 2; tt++) {
        int t = w * 2 + tt;
        gload16(Kb + base + (size_t)(j1 + 8 * t + lr) * 64 + scol, &Ks[nxt][t * 512]);
        gload16(VT + base + (size_t)(8 * t + lr) * 1024 + j1 + scol, &VTs[nxt][t * 512]);
      }
    }
    const u16* K_ = Ks[cur];
    const u16* V_ = VTs[cur];

    f32x4 accs[2][4];
    #pragma unroll
    for (int i = 0; i < 2; i++)
      #pragma unroll
      for (int nt = 0; nt < 4; nt++) accs[i][nt] = (f32x4){0.f, 0.f, 0.f, 0.f};
    #pragma unroll
    for (int s = 0; s < 2; s++) {
      bf16x8 bk[4];
      #pragma unroll
      for (int nt = 0; nt < 4; nt++)
        bk[nt] = *(const bf16x8*)&K_[swz(nt * 16 + (lane & 15), s * 32 + (lane >> 4) * 8)];
      __builtin_amdgcn_s_setprio(1);
      #pragma unroll
      for (int i = 0; i < 2; i++)
        #pragma unroll
        for (int nt = 0; nt < 4; nt++)
          accs[i][nt] = mfma16(aq[i][s], bk[nt], accs[i][nt]);
      __builtin_amdgcn_s_setprio(0);
    }

    #pragma unroll
    for (int i = 0; i < 2; i++) {
      #pragma unroll
      for (int nt = 0; nt < 4; nt++) {
        #pragma unroll
        for (int r = 0; r < 4; r++) {
          float p = __builtin_amdgcn_exp2f(accs[i][nt][r]);
          lpar[i][r] += p;
          Ps[w][swz(i * 16 + (lane >> 4) * 4 + r, nt * 16 + (lane & 15))] = f2bf(p);
        }
      }
    }
    asm volatile("s_waitcnt lgkmcnt(0)" ::: "memory");

    #pragma unroll
    for (int s = 0; s < 2; s++) {
      bf16x8 bv[4];
      #pragma unroll
      for (int dt = 0; dt < 4; dt++)
        bv[dt] = *(const bf16x8*)&V_[swz(dt * 16 + (lane & 15), s * 32 + (lane >> 4) * 8)];
      bf16x8 ap0 = *(const bf16x8*)&Ps[w][swz(0 * 16 + (lane & 15), s * 32 + (lane >> 4) * 8)];
      bf16x8 ap1 = *(const bf16x8*)&Ps[w][swz(1 * 16 + (lane & 15), s * 32 + (lane >> 4) * 8)];
      __builtin_amdgcn_s_setprio(1);
      #pragma unroll
      for (int dt = 0; dt < 4; dt++) {
        acc_o[0][dt] = mfma16(ap0, bv[dt], acc_o[0][dt]);
        acc_o[1][dt] = mfma16(ap1, bv[dt], acc_o[1][dt]);
      }
      __builtin_amdgcn_s_setprio(0);
    }
  }

  #pragma unroll
  for (int i = 0; i < 2; i++) {
    float inv[4];
    #pragma unroll
    for (int r = 0; r < 4; r++) {
      float l = lpar[i][r];
      #pragma unroll
      for (int m = 1; m < 16; m <<= 1) l += __shfl_xor(l, m);
      inv[r] = 1.0f / l;
    }
    #pragma unroll
    for (int dt = 0; dt < 4; dt++)
      #pragma unroll
      for (int r = 0; r < 4; r++) {
        int row = q0 + w * 32 + i * 16 + (lane >> 4) * 4 + r;
        int col = h * 64 + dt * 16 + (lane & 15);
        Ob[((size_t)b * 1024 + row) * 1024 + col] = f2bf(acc_o[i][dt][r] * inv[r]);
      }
  }
}

// ---------------- launch ----------------
extern "C" void kernel_launch(void* const* d_in, const int* in_sizes, int n_in,
                              void* d_out, int out_size, void* d_ws, size_t ws_size,
                              hipStream_t stream) {
  const float* x     = (const float*)d_in[0];
  const float* temb  = (const float*)d_in[1];
  const float* cos_y = (const float*)d_in[2];
  const float* sin_y = (const float*)d_in[3];
  const float* cos_x = (const float*)d_in[4];
  const float* sin_x = (const float*)d_in[5];
  const float* Wqkv  = (const float*)d_in[6];
  const float* bqkv  = (const float*)d_in[7];
  const float* Wt    = (const float*)d_in[8];
  const float* bt    = (const float*)d_in[9];
  const float* Wp    = (const float*)d_in[10];
  const float* bp    = (const float*)d_in[11];
  const float* qn_w  = (const float*)d_in[12];
  const float* kn_w  = (const float*)d_in[13];
  float* out = (float*)d_out;

  char* ws = (char*)d_ws;
  u16*   x_bf  = (u16*)(ws);                  // 16 MB; reused as att after QKV GEMM
  u16*   WqkvT = (u16*)(ws + 16777216);       // 6 MB
  u16*   WpT   = (u16*)(ws + 23068672);       // 2 MB
  u16*   qkv   = (u16*)(ws + 25264128);       // 48 MB
  u16*   Qb    = (u16*)(ws + 75595776);       // 16 MB
  u16*   Kb    = (u16*)(ws + 92372992);       // 16 MB
  u16*   VTb   = (u16*)(ws + 109150208);      // 16 MB
  float* tpart = (float*)(ws + 125927424);    // 3 MB
  u16*   att   = x_bf;

  k_prep<<<9600, 256, 0, stream>>>(x, x_bf, Wqkv, WqkvT, Wp, WpT, temb, Wt, tpart);
  k_gemm<0><<<dim3(24, 32), 256, 0, stream>>>(x_bf, WqkvT, qkv, nullptr, nullptr,
                                              bt, bqkv, tpart, 1024, 3072);
  k_rrv<<<dim3(16, 16, 8), 256, 0, stream>>>(qkv, cos_y, sin_y, cos_x, sin_x,
                                             qn_w, kn_w, Qb, Kb, VTb);
  k_attn<<<dim3(128, 8), 256, 0, stream>>>(Qb, Kb, VTb, att);
  k_gemm<1><<<dim3(8, 32), 256, 0, stream>>>(att, WpT, nullptr, out, bp,
                                             nullptr, nullptr, nullptr, 1024, 1024);
}

// Round 6
// 269.498 us; speedup vs baseline: 1.1162x; 1.1162x over previous
//
#include <hip/hip_runtime.h>
#include <cstdint>

typedef unsigned short u16;
typedef __bf16 bf16x8 __attribute__((ext_vector_type(8)));
typedef float f32x4 __attribute__((ext_vector_type(4)));

__device__ __forceinline__ u16 f2bf(float f) {
  __bf16 h = (__bf16)f;               // HW v_cvt (RNE) on gfx950
  return __builtin_bit_cast(u16, h);
}
__device__ __forceinline__ float bf2f(u16 u) {
  union { uint32_t u; float f; } v; v.u = ((uint32_t)u) << 16;
  return v.f;
}

// async global->LDS, 16B per lane. LDS dest is wave-uniform base + lane*16.
__device__ __forceinline__ void gload16(const void* g, const void* l) {
  __builtin_amdgcn_global_load_lds(
      (const __attribute__((address_space(1))) uint32_t*)(uintptr_t)g,
      (__attribute__((address_space(3))) uint32_t*)(uintptr_t)l, 16, 0, 0);
}

__device__ __forceinline__ f32x4 mfma16(bf16x8 a, bf16x8 b, f32x4 c) {
  return __builtin_amdgcn_mfma_f32_16x16x32_bf16(a, b, c, 0, 0, 0);
}

// swizzled LDS offset for logical (row, col) in a [*][64] bf16 tile:
// 16B chunks XORed by row&7 -> conflict-free b128 reads (verified).
__device__ __forceinline__ int swz(int row, int col) {
  return row * 64 + ((((col >> 3) ^ (row & 7)) << 3) | (col & 7));
}

// ---------------- merged prep: cvt + 2 transposes + temb_part ----------------
__device__ __forceinline__ void transpose64(const float* __restrict__ src,
                                            u16* __restrict__ dst, int R, int Cc,
                                            int r0, int c0, u16* t) {
  #pragma unroll
  for (int i = 0; i < 16; i++) {
    int e = i * 256 + threadIdx.x;
    int rl = e >> 6, cl = e & 63;
    t[cl * 66 + rl] = f2bf(src[(size_t)(r0 + rl) * Cc + c0 + cl]);
  }
  __syncthreads();
  #pragma unroll
  for (int i = 0; i < 16; i++) {
    int e = i * 256 + threadIdx.x;
    int ro = e >> 6, co = e & 63;
    dst[(size_t)(c0 + ro) * R + r0 + co] = t[ro * 66 + co];
  }
}

// sections: [0,8192) cvt x->bf16 | [8192,8960) T(Wqkv) | [8960,9216) T(Wp)
//           [9216,9600) temb_part
__global__ __launch_bounds__(256)
void k_prep(const float* __restrict__ x, u16* __restrict__ x_bf,
            const float* __restrict__ Wqkv, u16* __restrict__ WqkvT,
            const float* __restrict__ Wp, u16* __restrict__ WpT,
            const float* __restrict__ temb, const float* __restrict__ Wt,
            float* __restrict__ tpart) {
  __shared__ u16 t[64 * 66];
  int bid = blockIdx.x;
  if (bid < 8192) {                              // ---- cvt (2M float4) ----
    int i = bid * 256 + threadIdx.x;
    float4 v = ((const float4*)x)[i];
    union { u16 s[4]; uint2 u; } o;
    o.s[0] = f2bf(v.x); o.s[1] = f2bf(v.y); o.s[2] = f2bf(v.z); o.s[3] = f2bf(v.w);
    ((uint2*)x_bf)[i] = o.u;
    return;
  }
  bid -= 8192;
  if (bid < 768) {                               // ---- transpose Wqkv [1024][3072] ----
    transpose64(Wqkv, WqkvT, 1024, 3072, (bid / 48) * 64, (bid % 48) * 64, t);
    return;
  }
  bid -= 768;
  if (bid < 256) {                               // ---- transpose Wp [1024][1024] ----
    transpose64(Wp, WpT, 1024, 1024, (bid / 16) * 64, (bid % 16) * 64, t);
    return;
  }
  bid -= 256;                                    // ---- temb_part (384 blocks) ----
  {
    const int j = (bid % 12) * 256 + threadIdx.x;   // 0..3071
    const int k0 = (bid / 12) * 32;
    float acc[8];
    #pragma unroll
    for (int b = 0; b < 8; b++) acc[b] = 0.f;
    #pragma unroll 4
    for (int k = k0; k < k0 + 32; k++) {
      float wv = Wt[(size_t)k * 3072 + j];
      #pragma unroll
      for (int b = 0; b < 8; b++) acc[b] += temb[b * 1024 + k] * wv;
    }
    float* p = tpart + (size_t)(bid / 12) * 24576 + j;
    #pragma unroll
    for (int b = 0; b < 8; b++) p[b * 3072] = acc[b];
  }
}

// ------------- QKV GEMM (session-best 4-wave core): qkv = x_bf @ WqkvT^T -------------
// Block 256M x 128N, 4 waves, wave tile 64M x 128N, BK=32, dbuf LDS (48 KiB),
// 1 barrier/iter, prefetch after barrier. temb_red folded into prologue (tcs).
__global__ __launch_bounds__(256, 2)
void k_gemm0(const u16* __restrict__ A, const u16* __restrict__ Bt,
             u16* __restrict__ outb,
             const float* __restrict__ bt, const float* __restrict__ bqkv,
             const float* __restrict__ tpart, int K, int Ntot) {
  __shared__ u16 As[2][8192];   // 256 rows x 32 (K32) u16, swizzled
  __shared__ u16 Bs[2][4096];   // 128 rows x 32
  __shared__ float tcs[128];
  const int m0 = blockIdx.y * 256;
  const int n0 = blockIdx.x * 128;
  const int lane = threadIdx.x & 63;
  const int w = threadIdx.x >> 6;
  const int l15 = lane & 15;
  const int fo = (((lane >> 4) ^ ((lane >> 1) & 3)) << 3);
  const int srow = lane >> 2;
  const int schunk = (((lane & 3) ^ ((lane >> 3) & 3)) << 3);

  // fold temb_red: per-block 128-col bias slice (batch-constant: 256-row
  // blocks never cross the 1024-row batch boundary)
  if (threadIdx.x < 128) {
    const int bidx = m0 >> 10;
    const int j = n0 + (int)threadIdx.x;
    float a = bt[j] + bqkv[j];
    #pragma unroll
    for (int kt = 0; kt < 32; kt++) a += tpart[(size_t)kt * 24576 + bidx * 3072 + j];
    tcs[threadIdx.x] = a;
  }
  asm volatile("" ::: "memory");

  f32x4 acc[4][8];
  #pragma unroll
  for (int i = 0; i < 4; i++)
    #pragma unroll
    for (int j = 0; j < 8; j++) acc[i][j] = (f32x4){0.f, 0.f, 0.f, 0.f};

  const u16* Ag = A + (size_t)(m0 + srow) * K + schunk;
  const u16* Bg = Bt + (size_t)(n0 + srow) * K + schunk;

  const int iters = K >> 5;
  #pragma unroll
  for (int tt = 0; tt < 4; tt++) {
    int t = w * 4 + tt;
    gload16(Ag + (size_t)(16 * t) * K, &As[0][t * 512]);
  }
  #pragma unroll
  for (int tt = 0; tt < 2; tt++) {
    int t = w * 2 + tt;
    gload16(Bg + (size_t)(16 * t) * K, &Bs[0][t * 512]);
  }

  for (int it = 0; it < iters; it++) {
    __syncthreads();
    const int cur = it & 1;
    if (it + 1 < iters) {
      const int nxt = cur ^ 1;
      const int k1 = (it + 1) << 5;
      #pragma unroll
      for (int tt = 0; tt < 4; tt++) {
        int t = w * 4 + tt;
        gload16(Ag + (size_t)(16 * t) * K + k1, &As[nxt][t * 512]);
      }
      #pragma unroll
      for (int tt = 0; tt < 2; tt++) {
        int t = w * 2 + tt;
        gload16(Bg + (size_t)(16 * t) * K + k1, &Bs[nxt][t * 512]);
      }
    }
    bf16x8 af[4], bfr[8];
    #pragma unroll
    for (int i = 0; i < 4; i++)
      af[i] = *(const bf16x8*)&As[cur][(w * 64 + 16 * i + l15) * 32 + fo];
    #pragma unroll
    for (int j = 0; j < 8; j++)
      bfr[j] = *(const bf16x8*)&Bs[cur][(16 * j + l15) * 32 + fo];
    #pragma unroll
    for (int i = 0; i < 4; i++)
      #pragma unroll
      for (int j = 0; j < 8; j++)
        acc[i][j] = mfma16(af[i], bfr[j], acc[i][j]);
  }

  const int rl = (lane >> 4) * 4;
  #pragma unroll
  for (int i = 0; i < 4; i++) {
    #pragma unroll
    for (int j = 0; j < 8; j++) {
      #pragma unroll
      for (int r = 0; r < 4; r++) {
        int grow = m0 + w * 64 + 16 * i + rl + r;
        int gcol = n0 + 16 * j + l15;
        float v = acc[i][j][r] + tcs[16 * j + l15];
        outb[(size_t)grow * Ntot + gcol] = f2bf(v);
      }
    }
  }
}

// ------------- proj GEMM (8-wave 2-phase core; grid=256 -> 1 block/CU,
// intra-block pipelining is the only overlap, measured win R1->R2) -------------
__global__ __launch_bounds__(512, 2)
void k_gemm1(const u16* __restrict__ A, const u16* __restrict__ Bt,
             float* __restrict__ outf, const float* __restrict__ bias,
             int K, int Ntot) {
  __shared__ __align__(16) u16 As[3][128 * 64];
  __shared__ __align__(16) u16 Bs[3][256 * 64];

  const int nb = (int)gridDim.x;
  const int bid = (int)blockIdx.x;
  const int sb = (bid & 7) * (nb >> 3) + (bid >> 3);
  const int NBN = Ntot >> 8;
  const int m0 = (sb / NBN) * 128;
  const int n0 = (sb % NBN) * 256;

  const int lane = threadIdx.x & 63;
  const int w = threadIdx.x >> 6;
  const int wm = w >> 2;
  const int wn = w & 3;
  const int l15 = lane & 15;
  const int g8 = (lane >> 4) * 8;
  const int lr = lane >> 3;
  const int schunk = ((lane & 7) ^ lr) * 8;

  const u16* Ag = A + (size_t)(m0 + w * 16 + lr) * K + schunk;
  const u16* Bg = Bt + (size_t)(n0 + lr) * K + schunk;

  f32x4 acc[4][4];
  #pragma unroll
  for (int i = 0; i < 4; i++)
    #pragma unroll
    for (int j = 0; j < 4; j++) acc[i][j] = (f32x4){0.f, 0.f, 0.f, 0.f};

  auto stageA_Blo = [&](int kt_, int buf_) {
    const int ko = kt_ << 6;
    #pragma unroll
    for (int t = 0; t < 2; t++) {
      int r0 = w * 16 + t * 8;
      gload16(Ag + (size_t)(t * 8) * K + ko, &As[buf_][r0 * 64]);
    }
    #pragma unroll
    for (int t = 0; t < 2; t++) {
      int f0 = w * 16 + t * 8;
      int r0 = (f0 >> 5) * 64 + (f0 & 31);
      gload16(Bg + (size_t)r0 * K + ko, &Bs[buf_][r0 * 64]);
    }
  };
  auto stageBhi = [&](int kt_, int buf_) {
    const int ko = kt_ << 6;
    #pragma unroll
    for (int t = 0; t < 2; t++) {
      int f0 = w * 16 + t * 8;
      int r0 = (f0 >> 5) * 64 + 32 + (f0 & 31);
      gload16(Bg + (size_t)r0 * K + ko, &Bs[buf_][r0 * 64]);
    }
  };

  const int NT = K >> 6;                          // 16
  stageA_Blo(0, 0); stageBhi(0, 0);
  stageA_Blo(1, 1); stageBhi(1, 1);
  asm volatile("s_waitcnt vmcnt(8)" ::: "memory");
  __builtin_amdgcn_s_barrier();
  asm volatile("" ::: "memory");

  int cur = 0;
  for (int kt = 0; kt < NT; kt++) {
    const int nxtbuf = cur + 2 >= 3 ? cur - 1 : cur + 2;

    bf16x8 af[2][4], bfr[2][4];
    #pragma unroll
    for (int s = 0; s < 2; s++)
      #pragma unroll
      for (int mf = 0; mf < 4; mf++)
        af[s][mf] = *(const bf16x8*)&As[cur][swz(wm * 64 + mf * 16 + l15, s * 32 + g8)];
    #pragma unroll
    for (int s = 0; s < 2; s++)
      #pragma unroll
      for (int nf = 0; nf < 2; nf++)
        bfr[s][nf] = *(const bf16x8*)&Bs[cur][swz(wn * 64 + nf * 16 + l15, s * 32 + g8)];
    if (kt + 2 < NT) stageA_Blo(kt + 2, nxtbuf);
    if (kt <= NT - 2) asm volatile("s_waitcnt vmcnt(6)" ::: "memory");
    else              asm volatile("s_waitcnt vmcnt(0)" ::: "memory");
    __builtin_amdgcn_s_barrier();
    asm volatile("" ::: "memory");
    __builtin_amdgcn_s_setprio(1);
    #pragma unroll
    for (int s = 0; s < 2; s++)
      #pragma unroll
      for (int mf = 0; mf < 4; mf++)
        #pragma unroll
        for (int nf = 0; nf < 2; nf++)
          acc[mf][nf] = mfma16(af[s][mf], bfr[s][nf], acc[mf][nf]);
    __builtin_amdgcn_s_setprio(0);

    #pragma unroll
    for (int s = 0; s < 2; s++)
      #pragma unroll
      for (int nf = 2; nf < 4; nf++)
        bfr[s][nf] = *(const bf16x8*)&Bs[cur][swz(wn * 64 + nf * 16 + l15, s * 32 + g8)];
    if (kt + 2 < NT) stageBhi(kt + 2, nxtbuf);
    if (kt < NT - 2)       asm volatile("s_waitcnt vmcnt(6)" ::: "memory");
    else if (kt == NT - 2) asm volatile("s_waitcnt vmcnt(2)" ::: "memory");
    else                   asm volatile("s_waitcnt vmcnt(0)" ::: "memory");
    __builtin_amdgcn_s_barrier();
    asm volatile("" ::: "memory");
    __builtin_amdgcn_s_setprio(1);
    #pragma unroll
    for (int s = 0; s < 2; s++)
      #pragma unroll
      for (int mf = 0; mf < 4; mf++)
        #pragma unroll
        for (int nf = 2; nf < 4; nf++)
          acc[mf][nf] = mfma16(af[s][mf], bfr[s][nf], acc[mf][nf]);
    __builtin_amdgcn_s_setprio(0);

    cur = cur + 1 >= 3 ? 0 : cur + 1;
  }

  const int rl = (lane >> 4) * 4;
  #pragma unroll
  for (int mf = 0; mf < 4; mf++) {
    #pragma unroll
    for (int nf = 0; nf < 4; nf++) {
      #pragma unroll
      for (int r = 0; r < 4; r++) {
        int grow = m0 + wm * 64 + mf * 16 + rl + r;
        int gcol = n0 + wn * 64 + nf * 16 + l15;
        outf[(size_t)grow * Ntot + gcol] = acc[mf][nf][r] + bias[gcol];
      }
    }
  }
}

// ------- fused per-head RMSNorm + axial RoPE (q,k) + V transpose -------
__global__ __launch_bounds__(256)
void k_rrv(const u16* __restrict__ qkv,
           const float* __restrict__ cos_y, const float* __restrict__ sin_y,
           const float* __restrict__ cos_x, const float* __restrict__ sin_x,
           const float* __restrict__ qn_w, const float* __restrict__ kn_w,
           u16* __restrict__ Qo, u16* __restrict__ Ko, u16* __restrict__ VT) {
  __shared__ u16 t[64 * 68];
  const int n0 = blockIdx.x * 64, h = blockIdx.y, b = blockIdx.z;
  const int bh = b * 16 + h;
  const int lane = threadIdx.x & 63, w = threadIdx.x >> 6;
  const int l15 = lane & 15, lg = lane >> 4;
  float4 qw = *(const float4*)(qn_w + l15 * 4);
  float4 kw = *(const float4*)(kn_w + l15 * 4);
  const float sgn = (lane & 4) ? 1.0f : -1.0f;
  const float* ct = (lane & 8) ? cos_x : cos_y;
  const float* st = (lane & 8) ? sin_x : sin_y;
  const float QSCALE = 0.18033688011112042f;     // log2(e)/8

  #pragma unroll
  for (int rr = 0; rr < 4; rr++) {
    int row = n0 + w * 16 + rr * 4 + lg;
    size_t src = (size_t)(b * 1024 + row) * 3072 + h * 64 + l15 * 4;
    uint2 qu = *(const uint2*)(qkv + src);
    uint2 ku = *(const uint2*)(qkv + src + 1024);
    float q[4], k[4];
    q[0] = bf2f((u16)qu.x); q[1] = bf2f((u16)(qu.x >> 16));
    q[2] = bf2f((u16)qu.y); q[3] = bf2f((u16)(qu.y >> 16));
    k[0] = bf2f((u16)ku.x); k[1] = bf2f((u16)(ku.x >> 16));
    k[2] = bf2f((u16)ku.y); k[3] = bf2f((u16)(ku.y >> 16));
    float sq = q[0]*q[0] + q[1]*q[1] + q[2]*q[2] + q[3]*q[3];
    float sk = k[0]*k[0] + k[1]*k[1] + k[2]*k[2] + k[3]*k[3];
    #pragma unroll
    for (int m = 1; m < 16; m <<= 1) {
      sq += __shfl_xor(sq, m);
      sk += __shfl_xor(sk, m);
    }
    float rq = rsqrtf(sq * (1.0f / 64.0f) + 1e-6f);
    float rk = rsqrtf(sk * (1.0f / 64.0f) + 1e-6f);
    float4 cc = *(const float4*)(ct + (size_t)row * 32 + (lane & 7) * 4);
    float4 ss = *(const float4*)(st + (size_t)row * 32 + (lane & 7) * 4);
    float qn[4], kn[4];
    qn[0] = q[0]*rq*qw.x; qn[1] = q[1]*rq*qw.y; qn[2] = q[2]*rq*qw.z; qn[3] = q[3]*rq*qw.w;
    kn[0] = k[0]*rk*kw.x; kn[1] = k[1]*rk*kw.y; kn[2] = k[2]*rk*kw.z; kn[3] = k[3]*rk*kw.w;
    float c[4] = {cc.x, cc.y, cc.z, cc.w};
    float s[4] = {ss.x, ss.y, ss.z, ss.w};
    union { u16 e[4]; uint2 u; } oq, ok;
    #pragma unroll
    for (int j = 0; j < 4; j++) {
      float qp = __shfl_xor(qn[j], 4);
      float kp = __shfl_xor(kn[j], 4);
      oq.e[j] = f2bf((qn[j] * c[j] + sgn * qp * s[j]) * QSCALE);
      ok.e[j] = f2bf(kn[j] * c[j] + sgn * kp * s[j]);
    }
    size_t dst = ((size_t)bh * 1024 + row) * 64 + l15 * 4;
    *(uint2*)(Qo + dst) = oq.u;
    *(uint2*)(Ko + dst) = ok.u;
  }

  // V transpose: qkv v-slice [n][d] -> VT [bh][d][n]
  #pragma unroll
  for (int i = 0; i < 4; i++) {
    int e = i * 256 + threadIdx.x;
    int n = e >> 4, dc = e & 15;
    uint2 v = *(const uint2*)(qkv + (size_t)(b * 1024 + n0 + n) * 3072 + 2048 + h * 64 + dc * 4);
    t[(dc * 4 + 0) * 68 + n] = (u16)v.x;
    t[(dc * 4 + 1) * 68 + n] = (u16)(v.x >> 16);
    t[(dc * 4 + 2) * 68 + n] = (u16)v.y;
    t[(dc * 4 + 3) * 68 + n] = (u16)(v.y >> 16);
  }
  __syncthreads();
  #pragma unroll
  for (int i = 0; i < 4; i++) {
    int e = i * 256 + threadIdx.x;
    int d = e >> 4, nc = e & 15;
    const u16* p = &t[d * 68 + nc * 4];
    uint2 o;
    o.x = (uint32_t)p[0] | ((uint32_t)p[1] << 16);
    o.y = (uint32_t)p[2] | ((uint32_t)p[3] << 16);
    *(uint2*)(VT + ((size_t)bh * 64 + d) * 1024 + n0 + nc * 4) = o;
  }
}

// ---------------- flash attention, swapped-QK + in-register P ----------------
// QK^T computed as mfma(K,Q) -> S^T: lane holds q = l15 (+16i), k = 16nt+4g+r.
// PV uses a k-axis permutation pi applied to BOTH P-frag and V-frag (MFMA sums
// over k, so any consistent permutation is identity): lane g's owned k-values
// {k : (k mod 16)>>2 == g} map to its A-frag chunk -> P-fragments built fully
// in-lane via v_cvt_pk_bf16_f32 (16/iter), V-frags via 16 ds_read_b64.
// Removes the P LDS round-trip (32 ds_write_b16 + lgkmcnt(0) + 4 ds_read_b128).
__global__ __launch_bounds__(256, 2)
void k_attn(const u16* __restrict__ Q, const u16* __restrict__ Kb,
            const u16* __restrict__ VT, u16* __restrict__ Ob) {
  __shared__ u16 Ks[2][4096], VTs[2][4096];
  const int lane = threadIdx.x & 63;
  const int w = threadIdx.x >> 6;
  const int bh = blockIdx.x;          // b*16+h : q-tiles of one bh co-locate on an XCD
  const int qt = blockIdx.y;
  const int b = bh >> 4, h = bh & 15;
  const size_t base = (size_t)bh * 65536;
  const int q0 = qt * 128;
  const int scol = ((lane & 7) ^ (lane >> 3)) * 8;
  const int lr = lane >> 3;
  const int l15 = lane & 15;
  const int g = lane >> 4;

  // Q fragments (pre-scaled by log2e/8 in k_rrv); same registers serve as
  // the B-operand of the swapped MFMA (A/B frags have identical lane layout).
  bf16x8 aq[2][2];
  #pragma unroll
  for (int i = 0; i < 2; i++)
    #pragma unroll
    for (int s = 0; s < 2; s++)
      aq[i][s] = *(const bf16x8*)(Q + base +
          (size_t)(q0 + w * 32 + i * 16 + l15) * 64 + s * 32 + g * 8);

  f32x4 acc_o[2][4];
  float lpar[2] = {0.f, 0.f};
  #pragma unroll
  for (int i = 0; i < 2; i++)
    #pragma unroll
    for (int dt = 0; dt < 4; dt++) acc_o[i][dt] = (f32x4){0.f, 0.f, 0.f, 0.f};

  #pragma unroll
  for (int tt = 0; tt < 2; tt++) {
    int t = w * 2 + tt;
    gload16(Kb + base + (size_t)(8 * t + lr) * 64 + scol, &Ks[0][t * 512]);
    gload16(VT + base + (size_t)(8 * t + lr) * 1024 + scol, &VTs[0][t * 512]);
  }

  for (int it = 0; it < 16; it++) {
    __syncthreads();
    const int cur = it & 1;
    if (it < 15) {
      const int nxt = cur ^ 1;
      const int j1 = (it + 1) * 64;
      #pragma unroll
      for (int tt = 0; tt < 2; tt++) {
        int t = w * 2 + tt;
        gload16(Kb + base + (size_t)(j1 + 8 * t + lr) * 64 + scol, &Ks[nxt][t * 512]);
        gload16(VT + base + (size_t)(8 * t + lr) * 1024 + j1 + scol, &VTs[nxt][t * 512]);
      }
    }
    const u16* K_ = Ks[cur];
    const u16* V_ = VTs[cur];

    // S^T = K Q^T (exp2 domain): accs[i][nt][r] for q=l15+16i, k=16nt+4g+r
    f32x4 accs[2][4];
    #pragma unroll
    for (int i = 0; i < 2; i++)
      #pragma unroll
      for (int nt = 0; nt < 4; nt++) accs[i][nt] = (f32x4){0.f, 0.f, 0.f, 0.f};
    #pragma unroll
    for (int s = 0; s < 2; s++) {
      bf16x8 bk[4];
      #pragma unroll
      for (int nt = 0; nt < 4; nt++)
        bk[nt] = *(const bf16x8*)&K_[swz(nt * 16 + l15, s * 32 + g * 8)];
      __builtin_amdgcn_s_setprio(1);
      #pragma unroll
      for (int i = 0; i < 2; i++)
        #pragma unroll
        for (int nt = 0; nt < 4; nt++)
          accs[i][nt] = mfma16(bk[nt], aq[i][s], accs[i][nt]);
      __builtin_amdgcn_s_setprio(0);
    }

    // P = exp2(S^T); l partials (per-lane scalar, q = l15)
    float p[2][4][4];
    #pragma unroll
    for (int i = 0; i < 2; i++)
      #pragma unroll
      for (int nt = 0; nt < 4; nt++)
        #pragma unroll
        for (int r = 0; r < 4; r++) {
          p[i][nt][r] = __builtin_amdgcn_exp2f(accs[i][nt][r]);
          lpar[i] += p[i][nt][r];
        }

    // O += P V under permutation pi: frag pos e (0..7) <-> k = 32s+16(e>>2)+4g+(e&3)
    #pragma unroll
    for (int s = 0; s < 2; s++) {
      union { uint32_t u[4]; bf16x8 v; } ap[2];
      #pragma unroll
      for (int i = 0; i < 2; i++)
        #pragma unroll
        for (int m = 0; m < 4; m++)
          asm("v_cvt_pk_bf16_f32 %0, %1, %2"
              : "=v"(ap[i].u[m])
              : "v"(p[i][2 * s + (m >> 1)][2 * (m & 1)]),
                "v"(p[i][2 * s + (m >> 1)][2 * (m & 1) + 1]));
      bf16x8 bv[4];
      #pragma unroll
      for (int dt = 0; dt < 4; dt++) {
        union { uint2 x2[2]; bf16x8 v; } bb;
        bb.x2[0] = *(const uint2*)&V_[swz(dt * 16 + l15, s * 32 + 4 * g)];
        bb.x2[1] = *(const uint2*)&V_[swz(dt * 16 + l15, s * 32 + 16 + 4 * g)];
        bv[dt] = bb.v;
      }
      __builtin_amdgcn_s_setprio(1);
      #pragma unroll
      for (int dt = 0; dt < 4; dt++) {
        acc_o[0][dt] = mfma16(ap[0].v, bv[dt], acc_o[0][dt]);
        acc_o[1][dt] = mfma16(ap[1].v, bv[dt], acc_o[1][dt]);
      }
      __builtin_amdgcn_s_setprio(0);
    }
  }

  // epilogue: reduce l across g-groups (q = l15 column), redistribute to
  // O-rows (q = 16i + 4g + r), normalize, store
  #pragma unroll
  for (int i = 0; i < 2; i++) {
    float lred = lpar[i];
    lred += __shfl_xor(lred, 16);
    lred += __shfl_xor(lred, 32);
    float inv[4];
    #pragma unroll
    for (int r = 0; r < 4; r++) {
      float lv = __shfl(lred, 4 * g + r);   // lane with l15 == 4g+r holds l(q)
      inv[r] = 1.0f / lv;
    }
    #pragma unroll
    for (int dt = 0; dt < 4; dt++)
      #pragma unroll
      for (int r = 0; r < 4; r++) {
        int row = q0 + w * 32 + i * 16 + 4 * g + r;
        int col = h * 64 + dt * 16 + l15;
        Ob[((size_t)b * 1024 + row) * 1024 + col] = f2bf(acc_o[i][dt][r] * inv[r]);
      }
  }
}

// ---------------- launch ----------------
extern "C" void kernel_launch(void* const* d_in, const int* in_sizes, int n_in,
                              void* d_out, int out_size, void* d_ws, size_t ws_size,
                              hipStream_t stream) {
  const float* x     = (const float*)d_in[0];
  const float* temb  = (const float*)d_in[1];
  const float* cos_y = (const float*)d_in[2];
  const float* sin_y = (const float*)d_in[3];
  const float* cos_x = (const float*)d_in[4];
  const float* sin_x = (const float*)d_in[5];
  const float* Wqkv  = (const float*)d_in[6];
  const float* bqkv  = (const float*)d_in[7];
  const float* Wt    = (const float*)d_in[8];
  const float* bt    = (const float*)d_in[9];
  const float* Wp    = (const float*)d_in[10];
  const float* bp    = (const float*)d_in[11];
  const float* qn_w  = (const float*)d_in[12];
  const float* kn_w  = (const float*)d_in[13];
  float* out = (float*)d_out;

  char* ws = (char*)d_ws;
  u16*   x_bf  = (u16*)(ws);                  // 16 MB; reused as att after QKV GEMM
  u16*   WqkvT = (u16*)(ws + 16777216);       // 6 MB
  u16*   WpT   = (u16*)(ws + 23068672);       // 2 MB
  u16*   qkv   = (u16*)(ws + 25264128);       // 48 MB
  u16*   Qb    = (u16*)(ws + 75595776);       // 16 MB
  u16*   Kb    = (u16*)(ws + 92372992);       // 16 MB
  u16*   VTb   = (u16*)(ws + 109150208);      // 16 MB
  float* tpart = (float*)(ws + 125927424);    // 3 MB
  u16*   att   = x_bf;

  k_prep<<<9600, 256, 0, stream>>>(x, x_bf, Wqkv, WqkvT, Wp, WpT, temb, Wt, tpart);
  k_gemm0<<<dim3(24, 32), 256, 0, stream>>>(x_bf, WqkvT, qkv, bt, bqkv, tpart,
                                            1024, 3072);
  k_rrv<<<dim3(16, 16, 8), 256, 0, stream>>>(qkv, cos_y, sin_y, cos_x, sin_x,
                                             qn_w, kn_w, Qb, Kb, VTb);
  k_attn<<<dim3(128, 8), 256, 0, stream>>>(Qb, Kb, VTb, att);
  k_gemm1<<<dim3(256), 512, 0, stream>>>(att, WpT, out, bp, 1024, 1024);
}